// Round 9
// baseline (194.470 us; speedup 1.0000x reference)
//
#include <hip/hip_runtime.h>

#define N_NODES 50000
#define N_EDGES 800000
#define NBKT 196          // dest buckets of 256 nodes
#define BCAP 6144         // staging capacity per bucket (mean 4096 + 32 sigma)
#define ZROW 50000        // sentinel zero row in h16
#define UTS 136           // LDS tile row stride (halves); 272B = 16B-aligned, breaks 16-way conflicts

typedef __attribute__((ext_vector_type(4))) float floatx4;
typedef __attribute__((ext_vector_type(8))) _Float16 half8;

// ---- workspace layout (bytes) ----
#define O_PTR   0UL          // int[N] packed: (padded_start << 11) | (padded_deg/4)
#define O_GF    200192UL     // int[NBKT]
#define O_DINV  201472UL     // float[N]
#define O_ESRC  401664UL     // int[~950k] padded CSR, 3.81MB
#define O_W1    4204032UL    // f16[128*128] (transposed [n][k])
#define O_W2    4236800UL    // f16[64*128]  (transposed [n][k])
#define O_STG   4253184UL    // u32 staging[NBKT*BCAP] = 4.8MB
#define O_H16   16651008UL   // f16[(N+1)*128] dinv-prescaled h + zero row
// end: 29451264 bytes (<= 29.9MB proven footprint)

// Pass A: coarse-bin edges by dest>>8 into per-bucket staging runs.
__global__ __launch_bounds__(256) void k_binA(const int* __restrict__ ei,
                                              int* __restrict__ gfill,
                                              unsigned* __restrict__ staging) {
    __shared__ int cnt[NBKT];
    __shared__ int gbase[NBKT];
    __shared__ int s_i64;
    int t = threadIdx.x;
    if (t < 64) {                                  // wave 0: int64 probe
        unsigned w = ((const unsigned*)ei)[2 * t + 1];
        unsigned long long m = __ballot(w == 0u);
        if (t == 0) s_i64 = (__popcll(m) >= 60) ? 1 : 0;
    }
    for (int i = t; i < NBKT; i += 256) cnt[i] = 0;
    __syncthreads();
    bool i64 = s_i64 != 0;
    int e0 = blockIdx.x * 4096 + t * 16;           // 16 edges per thread
    int sv[16], dvv[16];
    if (i64) {
        const int4* ps = (const int4*)(ei) + (e0 >> 1);
        const int4* pd = (const int4*)(ei + 2 * (size_t)N_EDGES) + (e0 >> 1);
#pragma unroll
        for (int g = 0; g < 8; ++g) {
            if (e0 + 2 * g < N_EDGES) {
                int4 s4 = ps[g], d4 = pd[g];
                sv[2 * g] = s4.x; sv[2 * g + 1] = s4.z;
                dvv[2 * g] = d4.x; dvv[2 * g + 1] = d4.z;
            } else { dvv[2 * g] = -1; dvv[2 * g + 1] = -1; }
        }
    } else {
        const int4* ps = (const int4*)(ei) + (e0 >> 2);
        const int4* pd = (const int4*)(ei + (size_t)N_EDGES) + (e0 >> 2);
#pragma unroll
        for (int g = 0; g < 4; ++g) {
            if (e0 + 4 * g < N_EDGES) {
                int4 s4 = ps[g], d4 = pd[g];
                sv[4 * g] = s4.x; sv[4 * g + 1] = s4.y; sv[4 * g + 2] = s4.z; sv[4 * g + 3] = s4.w;
                dvv[4 * g] = d4.x; dvv[4 * g + 1] = d4.y; dvv[4 * g + 2] = d4.z; dvv[4 * g + 3] = d4.w;
            } else { dvv[4 * g] = -1; dvv[4 * g + 1] = -1; dvv[4 * g + 2] = -1; dvv[4 * g + 3] = -1; }
        }
    }
    unsigned pk[16]; int rk[16]; short bk[16];
#pragma unroll
    for (int j = 0; j < 16; ++j) {
        int d = dvv[j];
        if (d >= 0 && e0 + j < N_EDGES) {
            int b = d >> 8;
            bk[j] = (short)b;
            pk[j] = (unsigned)sv[j] | ((unsigned)(d & 255) << 16);
            rk[j] = atomicAdd(&cnt[b], 1);
        } else bk[j] = -1;
    }
    __syncthreads();
    for (int i = t; i < NBKT; i += 256)
        gbase[i] = atomicAdd(&gfill[i], cnt[i]);
    __syncthreads();
#pragma unroll
    for (int j = 0; j < 16; ++j) {
        if (bk[j] >= 0) {
            int pos = gbase[bk[j]] + rk[j];
            if (pos < BCAP) staging[(size_t)bk[j] * BCAP + pos] = pk[j];
        }
    }
}

// Pass B: per bucket -> padded edge CSR (packed ptr), dinv, prescaled h16.
// Blocks 0..95 also transpose one weight chunk; block 0 zeroes h16[ZROW].
__global__ __launch_bounds__(256) void k_binB(const unsigned* __restrict__ staging,
                                              const int* __restrict__ gfill,
                                              const float* __restrict__ h,
                                              const float* __restrict__ Wg,
                                              const float* __restrict__ Wf,
                                              int* __restrict__ ptr,
                                              float* __restrict__ dinv,
                                              _Float16* __restrict__ h16,
                                              _Float16* __restrict__ W1,
                                              _Float16* __restrict__ W2,
                                              int* __restrict__ esrc) {
    __shared__ unsigned se[BCAP];
    __shared__ int lcnt[256];
    __shared__ int lscan[256];
    __shared__ int cur[256];
    __shared__ float sdinv[256];
    __shared__ int s_cb;
    int b = blockIdx.x, t = threadIdx.x;
    if (b < 64) {
        int i = b * 256 + t;                       // W1: 16384 elems
        int n = i >> 7, k = i & 127;
        W1[i] = (_Float16)Wg[k * 128 + n];
    } else if (b < 96) {
        int i = (b - 64) * 256 + t;                // W2: 8192 elems
        int n = i >> 7, k = i & 127;
        W2[i] = (_Float16)Wf[k * 64 + n];
    } else if (b == 96 && t < 128) {
        h16[(size_t)ZROW * 128 + t] = (_Float16)0.f;   // sentinel zero row
    }
    int nbase = b * 256;
    int nn = min(256, N_NODES - nbase);
    int cnt = min(gfill[b], BCAP);
    if (t < 64) {                 // bucket base: sum_{i<b} min(gfill,BCAP) + b*768 pad reserve
        int acc = 0;
        for (int i = t; i < b; i += 64) acc += min(gfill[i], BCAP);
#pragma unroll
        for (int off = 32; off > 0; off >>= 1) acc += __shfl_down(acc, off);
        if (t == 0) s_cb = acc + b * 768;
    }
    lcnt[t] = 0;
    __syncthreads();
    int cb = s_cb;
    const unsigned* st = staging + (size_t)b * BCAP;
    for (int i = t; i < cnt; i += 256) {
        unsigned p = st[i];
        se[i] = p;
        atomicAdd(&lcnt[p >> 16], 1);
    }
    __syncthreads();
    int v = lcnt[t];
    int pv = (v + 3) & ~3;                         // padded deg (multiple of 4)
    lscan[t] = pv;
    __syncthreads();
    for (int off = 1; off < 256; off <<= 1) {
        int x = (t >= off) ? lscan[t - off] : 0;
        __syncthreads(); lscan[t] += x; __syncthreads();
    }
    int segstart = cb + (lscan[t] - pv);
    float dv = rsqrtf((float)(v + 1));             // real deg incl self-loop
    if (t < nn) {
        int node = nbase + t;
        ptr[node] = (segstart << 11) | (pv >> 2);  // packed
        dinv[node] = dv;
        sdinv[t] = dv;
        cur[t] = segstart;
        for (int i = v; i < pv; ++i) esrc[segstart + i] = ZROW;   // sentinel pad
    }
    __syncthreads();
    for (int i = t; i < cnt; i += 256) {           // single-pass scatter
        unsigned p = se[i];
        int pos = atomicAdd(&cur[p >> 16], 1);
        esrc[pos] = (int)(p & 0xffffu);
    }
    int half = t >> 7;
    int col = t & 127;
    for (int r = half; r < nn; r += 2) {           // h16 = f16(h * dinv), coalesced
        int node = nbase + r;
        h16[(size_t)node * 128 + col] = (_Float16)(h[(size_t)node * 128 + col] * sdinv[r]);
    }
}

// Fused aggregate + double GEMM. Block = 16 consecutive nodes (grid 3125).
// Gather: lane l covers row-in-group (l>>4), cols (l&15)*8 — one wave-load = 4 rows.
__global__ __launch_bounds__(256) void k_aggF(const _Float16* __restrict__ h16,
                                              const int* __restrict__ ptr,
                                              const int* __restrict__ esrc,
                                              const float* __restrict__ dinv,
                                              const _Float16* __restrict__ W1,
                                              const _Float16* __restrict__ W2,
                                              const float* __restrict__ bg,
                                              const float* __restrict__ bfc,
                                              float* __restrict__ out) {
    __shared__ _Float16 ut[16 * UTS];
    __shared__ _Float16 z[16 * UTS];
    int wave = threadIdx.x >> 6;
    int lane = threadIdx.x & 63;
    int nb = blockIdx.x * 16;
    int lane4 = lane >> 4;                 // row within 4-row group
    int colo = (lane & 15) * 8;            // col offset (halves)
    for (int q = 0; q < 4; ++q) {
        int node = nb + wave * 4 + q;
        int word = ptr[node];
        int base = word >> 11;
        int ngr = word & 0x7ff;            // number of 4-edge groups
        float acc[8];
        if (lane4 == 0) {                  // group 0 seeds with the self-loop row
            half8 us = *(const half8*)(h16 + (size_t)node * 128 + colo);
#pragma unroll
            for (int j = 0; j < 8; ++j) acc[j] = (float)us[j];
        } else {
#pragma unroll
            for (int j = 0; j < 8; ++j) acc[j] = 0.f;
        }
        for (int w = 0; w < ngr; w += 16) {
            int gmax = ngr - w; if (gmax > 16) gmax = 16;
            int idx = 0;
            if (lane < gmax * 4) idx = esrc[base + w * 4 + lane];
            if (gmax == 16) {
#pragma unroll
                for (int g = 0; g < 16; ++g) {
                    int row = __shfl(idx, g * 4 + lane4);
                    half8 u = *(const half8*)(h16 + (size_t)row * 128 + colo);
#pragma unroll
                    for (int j = 0; j < 8; ++j) acc[j] += (float)u[j];
                }
            } else {
                for (int g = 0; g < gmax; ++g) {
                    int row = __shfl(idx, g * 4 + lane4);
                    half8 u = *(const half8*)(h16 + (size_t)row * 128 + colo);
#pragma unroll
                    for (int j = 0; j < 8; ++j) acc[j] += (float)u[j];
                }
            }
        }
#pragma unroll
        for (int j = 0; j < 8; ++j) {      // fold the 4 lane-groups
            acc[j] += __shfl_xor(acc[j], 16);
            acc[j] += __shfl_xor(acc[j], 32);
        }
        if (lane < 16) {
            float sc = dinv[node];
            half8 o;
#pragma unroll
            for (int j = 0; j < 8; ++j) o[j] = (_Float16)(acc[j] * sc);
            *(half8*)(ut + (wave * 4 + q) * UTS + colo) = o;
        }
    }
    __syncthreads();
    int quad = lane >> 4, l15 = lane & 15;
    half8 a[4];
#pragma unroll
    for (int kk = 0; kk < 4; ++kk)
        a[kk] = *(const half8*)(ut + l15 * UTS + kk * 32 + quad * 8);
#pragma unroll
    for (int tt = 0; tt < 2; ++tt) {               // GEMM1: wave does 2 of 8 n-tiles
        floatx4 acc = {0.f, 0.f, 0.f, 0.f};
        int n = (wave * 2 + tt) * 16 + l15;
#pragma unroll
        for (int kk = 0; kk < 4; ++kk) {
            half8 bb = *(const half8*)(W1 + n * 128 + kk * 32 + quad * 8);
            acc = __builtin_amdgcn_mfma_f32_16x16x32_f16(a[kk], bb, acc, 0, 0, 0);
        }
        float bias = bg[n];
#pragma unroll
        for (int i = 0; i < 4; ++i)
            z[(quad * 4 + i) * UTS + n] = (_Float16)fmaxf(acc[i] + bias, 0.f);
    }
    __syncthreads();
    half8 a2[4];
#pragma unroll
    for (int kk = 0; kk < 4; ++kk)
        a2[kk] = *(const half8*)(z + l15 * UTS + kk * 32 + quad * 8);
    {                                               // GEMM2: wave does 1 of 4 n-tiles
        floatx4 acc = {0.f, 0.f, 0.f, 0.f};
        int n = wave * 16 + l15;
#pragma unroll
        for (int kk = 0; kk < 4; ++kk) {
            half8 bb = *(const half8*)(W2 + n * 128 + kk * 32 + quad * 8);
            acc = __builtin_amdgcn_mfma_f32_16x16x32_f16(a2[kk], bb, acc, 0, 0, 0);
        }
        float bias = bfc[n];
#pragma unroll
        for (int i = 0; i < 4; ++i)
            out[(size_t)(nb + quad * 4 + i) * 64 + n] = acc[i] + bias;
    }
}

extern "C" void kernel_launch(void* const* d_in, const int* in_sizes, int n_in,
                              void* d_out, int out_size, void* d_ws, size_t ws_size,
                              hipStream_t stream) {
    (void)in_sizes; (void)n_in; (void)out_size; (void)ws_size;
    const float* h  = (const float*)d_in[0];
    const int*   ei = (const int*)d_in[1];
    const float* Wg = (const float*)d_in[2];
    const float* bg = (const float*)d_in[3];
    const float* Wf = (const float*)d_in[4];
    const float* bf = (const float*)d_in[5];
    float* out = (float*)d_out;

    char* ws = (char*)d_ws;
    int*      ptr   = (int*)(ws + O_PTR);
    int*      gfill = (int*)(ws + O_GF);
    float*    dinv  = (float*)(ws + O_DINV);
    int*      esrc  = (int*)(ws + O_ESRC);
    _Float16* W1    = (_Float16*)(ws + O_W1);
    _Float16* W2    = (_Float16*)(ws + O_W2);
    unsigned* staging = (unsigned*)(ws + O_STG);
    _Float16* h16   = (_Float16*)(ws + O_H16);

    hipMemsetAsync(gfill, 0, NBKT * sizeof(int), stream);
    k_binA<<<NBKT, 256, 0, stream>>>(ei, gfill, staging);
    k_binB<<<NBKT, 256, 0, stream>>>(staging, gfill, h, Wg, Wf,
                                     ptr, dinv, h16, W1, W2, esrc);
    k_aggF<<<N_NODES / 16, 256, 0, stream>>>(h16, ptr, esrc, dinv,
                                             W1, W2, bg, bf, out);
}

// Round 10
// 154.883 us; speedup vs baseline: 1.2556x; 1.2556x over previous
//
#include <hip/hip_runtime.h>

#define N_NODES 50000
#define N_EDGES 800000
#define NBKT 196          // dest buckets of 256 nodes
#define BCAP 6144         // staging capacity per bucket (mean 4096 + 32 sigma)
#define UTS 136           // LDS tile row stride (halves); breaks the stride-128 16-way conflict

typedef __attribute__((ext_vector_type(4))) float floatx4;
typedef __attribute__((ext_vector_type(8))) _Float16 half8;
typedef __attribute__((ext_vector_type(2))) _Float16 half2v;

// ---- workspace layout (bytes) ----
#define O_PTR   0UL          // int[N] (edge-only CSR starts)
#define O_GF    200192UL     // int[NBKT]
#define O_DINV  201472UL     // float[N]
#define O_ESRC  401664UL     // int[N_EDGES] 3.2MB
#define O_W1    3801856UL    // f16[128*128] (transposed [n][k])
#define O_W2    3834624UL    // f16[64*128]  (transposed [n][k])
#define O_STG   3851008UL    // u32 staging[NBKT*BCAP] = 4.8MB
#define O_H16   16651008UL   // f16[N*128] dinv-prescaled h
// end: 29451008 bytes (<= 29.9MB proven footprint)

// Pass A: coarse-bin edges by dest>>8 into per-bucket staging runs.
// Index width (int32 vs int64) probed per-block from the first 64 odd words.
__global__ __launch_bounds__(256) void k_binA(const int* __restrict__ ei,
                                              int* __restrict__ gfill,
                                              unsigned* __restrict__ staging) {
    __shared__ int cnt[NBKT];
    __shared__ int gbase[NBKT];
    __shared__ int s_i64;
    int t = threadIdx.x;
    if (t < 64) {                                  // wave 0: int64 probe
        unsigned w = ((const unsigned*)ei)[2 * t + 1];
        unsigned long long m = __ballot(w == 0u);
        if (t == 0) s_i64 = (__popcll(m) >= 60) ? 1 : 0;
    }
    for (int i = t; i < NBKT; i += 256) cnt[i] = 0;
    __syncthreads();
    bool i64 = s_i64 != 0;
    int e0 = blockIdx.x * 4096 + t * 16;           // 16 edges per thread
    int sv[16], dvv[16];
    if (i64) {
        const int4* ps = (const int4*)(ei) + (e0 >> 1);
        const int4* pd = (const int4*)(ei + 2 * (size_t)N_EDGES) + (e0 >> 1);
#pragma unroll
        for (int g = 0; g < 8; ++g) {
            if (e0 + 2 * g < N_EDGES) {
                int4 s4 = ps[g], d4 = pd[g];
                sv[2 * g] = s4.x; sv[2 * g + 1] = s4.z;
                dvv[2 * g] = d4.x; dvv[2 * g + 1] = d4.z;
            } else { dvv[2 * g] = -1; dvv[2 * g + 1] = -1; }
        }
    } else {
        const int4* ps = (const int4*)(ei) + (e0 >> 2);
        const int4* pd = (const int4*)(ei + (size_t)N_EDGES) + (e0 >> 2);
#pragma unroll
        for (int g = 0; g < 4; ++g) {
            if (e0 + 4 * g < N_EDGES) {
                int4 s4 = ps[g], d4 = pd[g];
                sv[4 * g] = s4.x; sv[4 * g + 1] = s4.y; sv[4 * g + 2] = s4.z; sv[4 * g + 3] = s4.w;
                dvv[4 * g] = d4.x; dvv[4 * g + 1] = d4.y; dvv[4 * g + 2] = d4.z; dvv[4 * g + 3] = d4.w;
            } else { dvv[4 * g] = -1; dvv[4 * g + 1] = -1; dvv[4 * g + 2] = -1; dvv[4 * g + 3] = -1; }
        }
    }
    unsigned pk[16]; int rk[16]; short bk[16];
#pragma unroll
    for (int j = 0; j < 16; ++j) {
        int d = dvv[j];
        if (d >= 0 && e0 + j < N_EDGES) {
            int b = d >> 8;
            bk[j] = (short)b;
            pk[j] = (unsigned)sv[j] | ((unsigned)(d & 255) << 16);
            rk[j] = atomicAdd(&cnt[b], 1);
        } else bk[j] = -1;
    }
    __syncthreads();
    for (int i = t; i < NBKT; i += 256)
        gbase[i] = atomicAdd(&gfill[i], cnt[i]);
    __syncthreads();
#pragma unroll
    for (int j = 0; j < 16; ++j) {
        if (bk[j] >= 0) {
            int pos = gbase[bk[j]] + rk[j];
            if (pos < BCAP) staging[(size_t)bk[j] * BCAP + pos] = pk[j];
        }
    }
}

// Pass B: per bucket -> edge-only CSR, dinv, dinv-prescaled h16.
// Blocks 0..95 additionally transpose one 256-elem weight chunk to f16.
__global__ __launch_bounds__(256) void k_binB(const unsigned* __restrict__ staging,
                                              const int* __restrict__ gfill,
                                              const float* __restrict__ h,
                                              const float* __restrict__ Wg,
                                              const float* __restrict__ Wf,
                                              int* __restrict__ ptr,
                                              float* __restrict__ dinv,
                                              _Float16* __restrict__ h16,
                                              _Float16* __restrict__ W1,
                                              _Float16* __restrict__ W2,
                                              int* __restrict__ esrc) {
    __shared__ unsigned se[BCAP];
    __shared__ int lcnt[256];
    __shared__ int lscan[256];
    __shared__ int cur[256];
    __shared__ float sdinv[256];
    __shared__ int s_cb;
    int b = blockIdx.x, t = threadIdx.x;
    if (b < 64) {
        int i = b * 256 + t;                       // W1: 16384 elems
        int n = i >> 7, k = i & 127;
        W1[i] = (_Float16)Wg[k * 128 + n];
    } else if (b < 96) {
        int i = (b - 64) * 256 + t;                // W2: 8192 elems
        int n = i >> 7, k = i & 127;
        W2[i] = (_Float16)Wf[k * 64 + n];
    }
    int nbase = b * 256;
    int nn = min(256, N_NODES - nbase);
    int cnt = min(gfill[b], BCAP);
    if (t < 64) {                                  // edge-CSR base: sum_{i<b} edges_i
        int acc = 0;
        for (int i = t; i < b; i += 64) acc += min(gfill[i], BCAP);
#pragma unroll
        for (int off = 32; off > 0; off >>= 1) acc += __shfl_down(acc, off);
        if (t == 0) s_cb = acc;
    }
    lcnt[t] = 0;
    __syncthreads();
    int cb = s_cb;
    const unsigned* st = staging + (size_t)b * BCAP;
    for (int i = t; i < cnt; i += 256) {
        unsigned p = st[i];
        se[i] = p;
        atomicAdd(&lcnt[p >> 16], 1);
    }
    __syncthreads();
    int v = lcnt[t];
    lscan[t] = v;
    __syncthreads();
    for (int off = 1; off < 256; off <<= 1) {
        int x = (t >= off) ? lscan[t - off] : 0;
        __syncthreads(); lscan[t] += x; __syncthreads();
    }
    int segstart = cb + (lscan[t] - v);
    float dv = rsqrtf((float)(v + 1));             // +1 = self-loop (analytic in k_aggF)
    if (t < nn) {
        int node = nbase + t;
        ptr[node] = segstart;
        dinv[node] = dv;
        sdinv[t] = dv;
        cur[t] = segstart;
    }
    __syncthreads();
    for (int i = t; i < cnt; i += 256) {           // single-pass scatter
        unsigned p = se[i];
        int pos = atomicAdd(&cur[p >> 16], 1);
        esrc[pos] = (int)(p & 0xffffu);
    }
    int half = t >> 7;
    int col = t & 127;
    for (int r = half; r < nn; r += 2) {           // h16 = f16(h * dinv), coalesced
        int node = nbase + r;
        h16[(size_t)node * 128 + col] = (_Float16)(h[(size_t)node * 128 + col] * sdinv[r]);
    }
}

// Fused aggregate + double GEMM. Block = 16 consecutive nodes (grid 3125).
// Gather: round-8 proven form — half2/lane loads, 8-deep MLP, VGPR-lean
// (min 8 waves/EU pinned via launch_bounds; round-9's 16B gather halved
// occupancy 57->27% and cost +30us).
__global__ __launch_bounds__(256, 8) void k_aggF(const _Float16* __restrict__ h16,
                                                 const int* __restrict__ ptr,
                                                 const int* __restrict__ esrc,
                                                 const float* __restrict__ dinv,
                                                 const _Float16* __restrict__ W1,
                                                 const _Float16* __restrict__ W2,
                                                 const float* __restrict__ bg,
                                                 const float* __restrict__ bfc,
                                                 float* __restrict__ out) {
    __shared__ _Float16 ut[16 * UTS];
    __shared__ _Float16 z[16 * UTS];
    int wave = threadIdx.x >> 6;
    int lane = threadIdx.x & 63;
    int nb = blockIdx.x * 16;
    for (int q = 0; q < 4; ++q) {
        int node = nb + wave * 4 + q;
        int p0 = ptr[node];
        int p1 = (node + 1 < N_NODES) ? ptr[node + 1] : N_EDGES;
        half2v us = *(const half2v*)(h16 + (size_t)node * 128 + lane * 2);
        float a0 = (float)us[0], a1 = (float)us[1];           // self-loop
        for (int base = p0; base < p1; base += 64) {
            int cnt = p1 - base; if (cnt > 64) cnt = 64;
            int idx = 0;
            if (lane < cnt) idx = esrc[base + lane];
            int j = 0;
            for (; j + 8 <= cnt; j += 8) {
                int s0 = __shfl(idx, j),     s1 = __shfl(idx, j + 1);
                int s2 = __shfl(idx, j + 2), s3 = __shfl(idx, j + 3);
                int s4 = __shfl(idx, j + 4), s5 = __shfl(idx, j + 5);
                int s6 = __shfl(idx, j + 6), s7 = __shfl(idx, j + 7);
                half2v u0 = *(const half2v*)(h16 + (size_t)s0 * 128 + lane * 2);
                half2v u1 = *(const half2v*)(h16 + (size_t)s1 * 128 + lane * 2);
                half2v u2 = *(const half2v*)(h16 + (size_t)s2 * 128 + lane * 2);
                half2v u3 = *(const half2v*)(h16 + (size_t)s3 * 128 + lane * 2);
                half2v u4 = *(const half2v*)(h16 + (size_t)s4 * 128 + lane * 2);
                half2v u5 = *(const half2v*)(h16 + (size_t)s5 * 128 + lane * 2);
                half2v u6 = *(const half2v*)(h16 + (size_t)s6 * 128 + lane * 2);
                half2v u7 = *(const half2v*)(h16 + (size_t)s7 * 128 + lane * 2);
                a0 += (float)u0[0] + (float)u1[0] + (float)u2[0] + (float)u3[0]
                    + (float)u4[0] + (float)u5[0] + (float)u6[0] + (float)u7[0];
                a1 += (float)u0[1] + (float)u1[1] + (float)u2[1] + (float)u3[1]
                    + (float)u4[1] + (float)u5[1] + (float)u6[1] + (float)u7[1];
            }
            for (; j + 4 <= cnt; j += 4) {
                int s0 = __shfl(idx, j),     s1 = __shfl(idx, j + 1);
                int s2 = __shfl(idx, j + 2), s3 = __shfl(idx, j + 3);
                half2v u0 = *(const half2v*)(h16 + (size_t)s0 * 128 + lane * 2);
                half2v u1 = *(const half2v*)(h16 + (size_t)s1 * 128 + lane * 2);
                half2v u2 = *(const half2v*)(h16 + (size_t)s2 * 128 + lane * 2);
                half2v u3 = *(const half2v*)(h16 + (size_t)s3 * 128 + lane * 2);
                a0 += (float)u0[0] + (float)u1[0] + (float)u2[0] + (float)u3[0];
                a1 += (float)u0[1] + (float)u1[1] + (float)u2[1] + (float)u3[1];
            }
            for (; j < cnt; ++j) {
                int s = __shfl(idx, j);
                half2v uu = *(const half2v*)(h16 + (size_t)s * 128 + lane * 2);
                a0 += (float)uu[0]; a1 += (float)uu[1];
            }
        }
        float sc = dinv[node];
        int r = wave * 4 + q;
        ut[r * UTS + lane * 2]     = (_Float16)(a0 * sc);
        ut[r * UTS + lane * 2 + 1] = (_Float16)(a1 * sc);
    }
    __syncthreads();
    int quad = lane >> 4, l15 = lane & 15;
    half8 a[4];
#pragma unroll
    for (int kk = 0; kk < 4; ++kk)
        a[kk] = *(const half8*)(ut + l15 * UTS + kk * 32 + quad * 8);
#pragma unroll
    for (int tt = 0; tt < 2; ++tt) {               // GEMM1: wave does 2 of 8 n-tiles
        floatx4 acc = {0.f, 0.f, 0.f, 0.f};
        int n = (wave * 2 + tt) * 16 + l15;
#pragma unroll
        for (int kk = 0; kk < 4; ++kk) {
            half8 bb = *(const half8*)(W1 + n * 128 + kk * 32 + quad * 8);
            acc = __builtin_amdgcn_mfma_f32_16x16x32_f16(a[kk], bb, acc, 0, 0, 0);
        }
        float bias = bg[n];
#pragma unroll
        for (int i = 0; i < 4; ++i)
            z[(quad * 4 + i) * UTS + n] = (_Float16)fmaxf(acc[i] + bias, 0.f);
    }
    __syncthreads();
    half8 a2[4];
#pragma unroll
    for (int kk = 0; kk < 4; ++kk)
        a2[kk] = *(const half8*)(z + l15 * UTS + kk * 32 + quad * 8);
    {                                               // GEMM2: wave does 1 of 4 n-tiles
        floatx4 acc = {0.f, 0.f, 0.f, 0.f};
        int n = wave * 16 + l15;
#pragma unroll
        for (int kk = 0; kk < 4; ++kk) {
            half8 bb = *(const half8*)(W2 + n * 128 + kk * 32 + quad * 8);
            acc = __builtin_amdgcn_mfma_f32_16x16x32_f16(a2[kk], bb, acc, 0, 0, 0);
        }
        float bias = bfc[n];
#pragma unroll
        for (int i = 0; i < 4; ++i)
            out[(size_t)(nb + quad * 4 + i) * 64 + n] = acc[i] + bias;
    }
}

extern "C" void kernel_launch(void* const* d_in, const int* in_sizes, int n_in,
                              void* d_out, int out_size, void* d_ws, size_t ws_size,
                              hipStream_t stream) {
    (void)in_sizes; (void)n_in; (void)out_size; (void)ws_size;
    const float* h  = (const float*)d_in[0];
    const int*   ei = (const int*)d_in[1];
    const float* Wg = (const float*)d_in[2];
    const float* bg = (const float*)d_in[3];
    const float* Wf = (const float*)d_in[4];
    const float* bf = (const float*)d_in[5];
    float* out = (float*)d_out;

    char* ws = (char*)d_ws;
    int*      ptr   = (int*)(ws + O_PTR);
    int*      gfill = (int*)(ws + O_GF);
    float*    dinv  = (float*)(ws + O_DINV);
    int*      esrc  = (int*)(ws + O_ESRC);
    _Float16* W1    = (_Float16*)(ws + O_W1);
    _Float16* W2    = (_Float16*)(ws + O_W2);
    unsigned* staging = (unsigned*)(ws + O_STG);
    _Float16* h16   = (_Float16*)(ws + O_H16);

    hipMemsetAsync(gfill, 0, NBKT * sizeof(int), stream);
    k_binA<<<NBKT, 256, 0, stream>>>(ei, gfill, staging);
    k_binB<<<NBKT, 256, 0, stream>>>(staging, gfill, h, Wg, Wf,
                                     ptr, dinv, h16, W1, W2, esrc);
    k_aggF<<<N_NODES / 16, 256, 0, stream>>>(h16, ptr, esrc, dinv,
                                             W1, W2, bg, bf, out);
}